// Round 1
// baseline (90.193 us; speedup 1.0000x reference)
//
#include <hip/hip_runtime.h>

#define KSIZE 5
#define PAD 2

// One thread per output pixel. Block = 256 consecutive pixels along W
// (W=512 -> 2 blocks/row, fully coalesced center loads; taps hit L1).
__global__ __launch_bounds__(256) void bilateral_kernel(
    const float* __restrict__ x,
    const float* __restrict__ sk,
    const float* __restrict__ sigma_color,
    float* __restrict__ out,
    int H, int W, int total)
{
    __shared__ float s_sk[KSIZE * KSIZE];
    __shared__ float s_c2;  // -log2(e) / (2*sigma^2)

    int t = threadIdx.x;
    if (t < KSIZE * KSIZE) s_sk[t] = sk[t];
    if (t == KSIZE * KSIZE) {
        float sc = sigma_color[0];
        s_c2 = -1.4426950408889634f / (2.0f * sc * sc);
    }
    __syncthreads();

    int idx = blockIdx.x * 256 + t;
    if (idx >= total) return;

    int w = idx % W;
    int hw = idx / W;
    int h = hw % H;
    int plane = hw / H;
    int base = plane * H * W;

    float cx = x[idx];
    float c2 = s_c2;

    // Branchless reflect (np/jnp 'reflect': -1 -> 1, H -> H-2)
    int hoff[KSIZE];
    int woff[KSIZE];
#pragma unroll
    for (int i = 0; i < KSIZE; ++i) {
        int hv = h + i - PAD;
        hv = (hv < 0) ? -hv : hv;
        hv = (hv >= H) ? (2 * H - 2 - hv) : hv;
        hoff[i] = hv * W;
    }
#pragma unroll
    for (int j = 0; j < KSIZE; ++j) {
        int wv = w + j - PAD;
        wv = (wv < 0) ? -wv : wv;
        wv = (wv >= W) ? (2 * W - 2 - wv) : wv;
        woff[j] = wv;
    }

    float wsum = 0.0f;
    float acc  = 0.0f;
#pragma unroll
    for (int i = 0; i < KSIZE; ++i) {
#pragma unroll
        for (int j = 0; j < KSIZE; ++j) {
            float p = x[base + hoff[i] + woff[j]];
            float d = p - cx;
            float wgt = s_sk[i * KSIZE + j] * __builtin_amdgcn_exp2f(d * d * c2);
            wsum += wgt;
            acc = fmaf(wgt, p, acc);
        }
    }

    out[idx] = acc * __builtin_amdgcn_rcpf(wsum + 1e-8f);
}

extern "C" void kernel_launch(void* const* d_in, const int* in_sizes, int n_in,
                              void* d_out, int out_size, void* d_ws, size_t ws_size,
                              hipStream_t stream) {
    const float* x  = (const float*)d_in[0];
    const float* sk = (const float*)d_in[1];
    const float* sc = (const float*)d_in[2];
    float* out = (float*)d_out;

    const int H = 512, W = 512;
    const int total = in_sizes[0];          // B*C*H*W = 3,145,728
    const int blocks = (total + 255) / 256; // 12288

    bilateral_kernel<<<blocks, 256, 0, stream>>>(x, sk, sc, out, H, W, total);
}

// Round 2
// 85.304 us; speedup vs baseline: 1.0573x; 1.0573x over previous
//
#include <hip/hip_runtime.h>

constexpr int H = 512, W = 512;   // fixed by the problem (4,3,512,512)
constexpr int K = 5, PADR = 2;

// 4 pixels per thread along W. Per row of the 5x8 window: one aligned float4
// (cols w0..w0+3) + 4 scalar halo loads with branchless reflect — uniform
// control flow, no divergent border path.
__global__ __launch_bounds__(256) void bilateral_kernel(
    const float* __restrict__ x,
    const float* __restrict__ sk,
    const float* __restrict__ sigma_color,
    float* __restrict__ out)
{
    __shared__ float s_lsk[K * K];
    __shared__ float s_c2;

    int t = threadIdx.x;
    if (t < K * K) s_lsk[t] = __builtin_amdgcn_logf(sk[t]);  // log2(sk)
    if (t == K * K) {
        float sc = sigma_color[0];
        s_c2 = -1.4426950408889634f / (2.0f * sc * sc);      // -log2(e)/(2s^2)
    }
    __syncthreads();

    float lsk[K * K];
#pragma unroll
    for (int k = 0; k < K * K; ++k) lsk[k] = s_lsk[k];
    float c2 = s_c2;

    int gid = blockIdx.x * 256 + t;
    int p0 = gid << 2;                   // first of 4 pixels (grid exactly covers)
    int w0 = p0 & (W - 1);               // multiple of 4 -> float4 aligned
    int row = p0 >> 9;                   // global row in [0, B*C*H)
    int h = row & (H - 1);
    int plane = row >> 9;
    const float* xp = x + (size_t)plane * (H * W);

    // reflected row offsets (np 'reflect': -1 -> 1, H -> H-2)
    int hoff[K];
#pragma unroll
    for (int i = 0; i < K; ++i) {
        int hv = h + i - PADR;
        hv = (hv < 0) ? -hv : hv;
        hv = (hv >= H) ? (2 * H - 2 - hv) : hv;
        hoff[i] = hv << 9;
    }
    // reflected halo columns (only w0==0 / w0==508 actually reflect)
    int wl0 = w0 - 2; wl0 = (wl0 < 0) ? -wl0 : wl0;
    int wl1 = w0 - 1; wl1 = (wl1 < 0) ? -wl1 : wl1;
    int wr0 = w0 + 4; wr0 = (wr0 >= W) ? (2 * W - 2 - wr0) : wr0;
    int wr1 = w0 + 5; wr1 = (wr1 >= W) ? (2 * W - 2 - wr1) : wr1;

    float win[K][8];
#pragma unroll
    for (int i = 0; i < K; ++i) {
        const float* rp = xp + hoff[i];
        float4 m = *(const float4*)(rp + w0);
        win[i][2] = m.x; win[i][3] = m.y; win[i][4] = m.z; win[i][5] = m.w;
        win[i][0] = rp[wl0];
        win[i][1] = rp[wl1];
        win[i][6] = rp[wr0];
        win[i][7] = rp[wr1];
    }

    float res[4];
#pragma unroll
    for (int p = 0; p < 4; ++p) {
        float cx = win[2][p + 2];
        float wsum = 0.0f, acc = 0.0f;
#pragma unroll
        for (int i = 0; i < K; ++i) {
#pragma unroll
            for (int j = 0; j < K; ++j) {
                float v = win[i][p + j];
                float d = v - cx;
                // sk * exp2(c2*d^2) == exp2(fma(d*c2, d, log2(sk)))
                float wgt = __builtin_amdgcn_exp2f(fmaf(d * c2, d, lsk[i * K + j]));
                wsum += wgt;
                acc = fmaf(wgt, v, acc);
            }
        }
        res[p] = acc * __builtin_amdgcn_rcpf(wsum + 1e-8f);
    }

    float4 o;
    o.x = res[0]; o.y = res[1]; o.z = res[2]; o.w = res[3];
    *(float4*)(out + p0) = o;
}

extern "C" void kernel_launch(void* const* d_in, const int* in_sizes, int n_in,
                              void* d_out, int out_size, void* d_ws, size_t ws_size,
                              hipStream_t stream) {
    const float* x  = (const float*)d_in[0];
    const float* sk = (const float*)d_in[1];
    const float* sc = (const float*)d_in[2];
    float* out = (float*)d_out;

    const int total = in_sizes[0];             // 3,145,728
    const int blocks = total / (256 * 4);      // 3072, exact cover
    bilateral_kernel<<<blocks, 256, 0, stream>>>(x, sk, sc, out);
}

// Round 3
// 83.641 us; speedup vs baseline: 1.0783x; 1.0199x over previous
//
#include <hip/hip_runtime.h>

typedef float v2f __attribute__((ext_vector_type(2)));

constexpr int H = 512, W = 512;   // fixed by the problem (4,3,512,512)
constexpr int K = 5, PADR = 2;

// Tiny prep: d_ws[0..24] = log2(spatial_kernel), d_ws[25] = -log2(e)/(2*sigma^2).
// Runs every call (d_ws is re-poisoned before each timed launch).
__global__ void prep_kernel(const float* __restrict__ sk,
                            const float* __restrict__ sigma_color,
                            float* __restrict__ lw) {
    int t = threadIdx.x;
    if (t < K * K) lw[t] = __builtin_amdgcn_logf(sk[t]);          // log2
    if (t == K * K) {
        float s = sigma_color[0];
        lw[K * K] = -1.4426950408889634f / (2.0f * s * s);
    }
}

// 4 pixels per thread along W, computed as two float2 lanes so the backend
// can emit packed fp32 (v_pk_fma_f32 etc). Spatial log-weights come in via
// wave-uniform loads -> SGPRs (1 SGPR operand per pk instr is legal).
__global__ __launch_bounds__(256) void bilateral_kernel(
    const float* __restrict__ x,
    const float* __restrict__ lw,
    float* __restrict__ out)
{
    float c2 = lw[K * K];            // uniform -> SGPR

    int t = threadIdx.x;
    int gid = blockIdx.x * 256 + t;
    int p0 = gid << 2;               // first of 4 pixels (grid exactly covers)
    int w0 = p0 & (W - 1);           // multiple of 4 -> float4 aligned
    int row = p0 >> 9;
    int h = row & (H - 1);
    int plane = row >> 9;
    const float* xp = x + (size_t)plane * (H * W);

    // reflected row offsets (np 'reflect': -1 -> 1, H -> H-2)
    int hoff[K];
#pragma unroll
    for (int i = 0; i < K; ++i) {
        int hv = h + i - PADR;
        hv = (hv < 0) ? -hv : hv;
        hv = (hv >= H) ? (2 * H - 2 - hv) : hv;
        hoff[i] = hv << 9;
    }
    // reflected halo columns (only w0==0 / w0==508 actually reflect)
    int wl0 = w0 - 2; wl0 = (wl0 < 0) ? -wl0 : wl0;
    int wl1 = w0 - 1; wl1 = (wl1 < 0) ? -wl1 : wl1;
    int wr0 = w0 + 4; wr0 = (wr0 >= W) ? (2 * W - 2 - wr0) : wr0;
    int wr1 = w0 + 5; wr1 = (wr1 >= W) ? (2 * W - 2 - wr1) : wr1;

    float win[K][8];
#pragma unroll
    for (int i = 0; i < K; ++i) {
        const float* rp = xp + hoff[i];
        float4 m = *(const float4*)(rp + w0);
        win[i][2] = m.x; win[i][3] = m.y; win[i][4] = m.z; win[i][5] = m.w;
        win[i][0] = rp[wl0];
        win[i][1] = rp[wl1];
        win[i][6] = rp[wr0];
        win[i][7] = rp[wr1];
    }

    v2f cA = { win[2][2], win[2][3] };
    v2f cB = { win[2][4], win[2][5] };
    v2f wsA = {0.f, 0.f}, wsB = {0.f, 0.f};
    v2f accA = {0.f, 0.f}, accB = {0.f, 0.f};

#pragma unroll
    for (int i = 0; i < K; ++i) {
#pragma unroll
        for (int j = 0; j < K; ++j) {
            float lwv = lw[i * K + j];         // uniform -> SGPR
            v2f lsp = { lwv, lwv };
            v2f vA = { win[i][j],     win[i][j + 1] };
            v2f vB = { win[i][j + 2], win[i][j + 3] };
            v2f dA = vA - cA;
            v2f dB = vB - cB;
            v2f aA = dA * c2;
            v2f aB = dB * c2;
            v2f argA = __builtin_elementwise_fma(aA, dA, lsp);
            v2f argB = __builtin_elementwise_fma(aB, dB, lsp);
            v2f wA, wB;
            wA[0] = __builtin_amdgcn_exp2f(argA[0]);
            wA[1] = __builtin_amdgcn_exp2f(argA[1]);
            wB[0] = __builtin_amdgcn_exp2f(argB[0]);
            wB[1] = __builtin_amdgcn_exp2f(argB[1]);
            wsA += wA;
            wsB += wB;
            accA = __builtin_elementwise_fma(wA, vA, accA);
            accB = __builtin_elementwise_fma(wB, vB, accB);
        }
    }

    float4 o;
    o.x = accA[0] * __builtin_amdgcn_rcpf(wsA[0] + 1e-8f);
    o.y = accA[1] * __builtin_amdgcn_rcpf(wsA[1] + 1e-8f);
    o.z = accB[0] * __builtin_amdgcn_rcpf(wsB[0] + 1e-8f);
    o.w = accB[1] * __builtin_amdgcn_rcpf(wsB[1] + 1e-8f);
    *(float4*)(out + p0) = o;
}

extern "C" void kernel_launch(void* const* d_in, const int* in_sizes, int n_in,
                              void* d_out, int out_size, void* d_ws, size_t ws_size,
                              hipStream_t stream) {
    const float* x  = (const float*)d_in[0];
    const float* sk = (const float*)d_in[1];
    const float* sc = (const float*)d_in[2];
    float* out = (float*)d_out;
    float* lw  = (float*)d_ws;                 // 26 floats of scratch

    prep_kernel<<<1, 64, 0, stream>>>(sk, sc, lw);

    const int total = in_sizes[0];             // 3,145,728
    const int blocks = total / (256 * 4);      // 3072, exact cover
    bilateral_kernel<<<blocks, 256, 0, stream>>>(x, lw, out);
}

// Round 4
// 82.658 us; speedup vs baseline: 1.0912x; 1.0119x over previous
//
#include <hip/hip_runtime.h>

typedef float v2f __attribute__((ext_vector_type(2)));

constexpr int H = 512, W = 512;   // fixed by the problem (4,3,512,512)
constexpr int K = 5, PADR = 2;

__device__ inline float readlane_f(float v, int l) {
    union { float f; int i; } u; u.f = v;
    u.i = __builtin_amdgcn_readlane(u.i, l);
    return u.f;
}

// 8 pixels per thread along W (4 v2f pairs). Window 5x12: two aligned float4
// loads + 4 scalar halo loads per row, branchless reflect. log2(spatial)
// broadcast to SGPRs via readlane — no prep kernel, no LDS, no barrier.
__global__ __launch_bounds__(256) void bilateral_kernel(
    const float* __restrict__ x,
    const float* __restrict__ sk,
    const float* __restrict__ sigma_color,
    float* __restrict__ out)
{
    int t = threadIdx.x;
    int lane = t & 63;

    // lanes 0..24 of every wave: vlog = log2(sk[lane]); broadcast via readlane
    float skl = sk[lane < K * K ? lane : 0];
    float vlog = __builtin_amdgcn_logf(skl);          // v_log_f32 = log2
    float lsk[K * K];
#pragma unroll
    for (int k = 0; k < K * K; ++k) lsk[k] = readlane_f(vlog, k);

    float s = sigma_color[0];                          // wave-uniform
    float c2 = -1.4426950408889634f / (2.0f * s * s);  // -log2(e)/(2s^2)
    v2f c2v = { c2, c2 };

    int gid = blockIdx.x * 256 + t;
    int p0 = gid << 3;                 // first of 8 pixels (grid exactly covers)
    int w0 = p0 & (W - 1);             // multiple of 8 -> float4 aligned x2
    int row = p0 >> 9;
    int h = row & (H - 1);
    int plane = row >> 9;
    const float* xp = x + (size_t)plane * (H * W);

    // reflected row offsets (np 'reflect': -1 -> 1, H -> H-2)
    int hoff[K];
#pragma unroll
    for (int i = 0; i < K; ++i) {
        int hv = h + i - PADR;
        hv = (hv < 0) ? -hv : hv;
        hv = (hv >= H) ? (2 * H - 2 - hv) : hv;
        hoff[i] = hv << 9;
    }
    // reflected halo columns (only w0==0 / w0==504 actually reflect)
    int wl0 = w0 - 2; wl0 = (wl0 < 0) ? -wl0 : wl0;
    int wl1 = w0 - 1; wl1 = (wl1 < 0) ? -wl1 : wl1;
    int wr0 = w0 + 8; wr0 = (wr0 >= W) ? (2 * W - 2 - wr0) : wr0;
    int wr1 = w0 + 9; wr1 = (wr1 >= W) ? (2 * W - 2 - wr1) : wr1;

    float win[K][12];
#pragma unroll
    for (int i = 0; i < K; ++i) {
        const float* rp = xp + hoff[i];
        float4 m0 = *(const float4*)(rp + w0);
        float4 m1 = *(const float4*)(rp + w0 + 4);
        win[i][2] = m0.x; win[i][3] = m0.y; win[i][4] = m0.z; win[i][5] = m0.w;
        win[i][6] = m1.x; win[i][7] = m1.y; win[i][8] = m1.z; win[i][9] = m1.w;
        win[i][0]  = rp[wl0];
        win[i][1]  = rp[wl1];
        win[i][10] = rp[wr0];
        win[i][11] = rp[wr1];
    }

    v2f cc[4], ws[4], acc[4];
#pragma unroll
    for (int q = 0; q < 4; ++q) {
        cc[q][0] = win[2][2 * q + 2];
        cc[q][1] = win[2][2 * q + 3];
        ws[q] = (v2f){0.f, 0.f};
        acc[q] = (v2f){0.f, 0.f};
    }

#pragma unroll
    for (int i = 0; i < K; ++i) {
#pragma unroll
        for (int j = 0; j < K; ++j) {
            float lwv = lsk[i * K + j];
            v2f lsp = { lwv, lwv };
#pragma unroll
            for (int q = 0; q < 4; ++q) {
                v2f v = { win[i][2 * q + j], win[i][2 * q + j + 1] };
                v2f d = v - cc[q];
                v2f arg = __builtin_elementwise_fma(d * c2v, d, lsp);
                v2f wq;
                wq[0] = __builtin_amdgcn_exp2f(arg[0]);
                wq[1] = __builtin_amdgcn_exp2f(arg[1]);
                ws[q] += wq;
                acc[q] = __builtin_elementwise_fma(wq, v, acc[q]);
            }
        }
    }

    float4 o0, o1;
    o0.x = acc[0][0] * __builtin_amdgcn_rcpf(ws[0][0] + 1e-8f);
    o0.y = acc[0][1] * __builtin_amdgcn_rcpf(ws[0][1] + 1e-8f);
    o0.z = acc[1][0] * __builtin_amdgcn_rcpf(ws[1][0] + 1e-8f);
    o0.w = acc[1][1] * __builtin_amdgcn_rcpf(ws[1][1] + 1e-8f);
    o1.x = acc[2][0] * __builtin_amdgcn_rcpf(ws[2][0] + 1e-8f);
    o1.y = acc[2][1] * __builtin_amdgcn_rcpf(ws[2][1] + 1e-8f);
    o1.z = acc[3][0] * __builtin_amdgcn_rcpf(ws[3][0] + 1e-8f);
    o1.w = acc[3][1] * __builtin_amdgcn_rcpf(ws[3][1] + 1e-8f);
    *(float4*)(out + p0)     = o0;
    *(float4*)(out + p0 + 4) = o1;
}

extern "C" void kernel_launch(void* const* d_in, const int* in_sizes, int n_in,
                              void* d_out, int out_size, void* d_ws, size_t ws_size,
                              hipStream_t stream) {
    const float* x  = (const float*)d_in[0];
    const float* sk = (const float*)d_in[1];
    const float* sc = (const float*)d_in[2];
    float* out = (float*)d_out;

    const int total = in_sizes[0];             // 3,145,728
    const int blocks = total / (256 * 8);      // 1536, exact cover
    bilateral_kernel<<<blocks, 256, 0, stream>>>(x, sk, sc, out);
}